// Round 11
// baseline (226.481 us; speedup 1.0000x reference)
//
#include <hip/hip_runtime.h>
#include <hip/hip_bf16.h>

#define KK 32
#define DD 128
#define NEGV (-1e9f)
#define SE 136   // LDS row stride in ushorts: 272 B, 16-B aligned, non-pow2 banks
#define PREP_BLKS 2048

typedef __attribute__((ext_vector_type(8))) short bf16x8;
typedef __attribute__((ext_vector_type(4))) float f32x4;

__device__ __forceinline__ unsigned short f2bf(float f) {
    union { float f; unsigned u; } v; v.f = f;
    unsigned r = v.u + 0x7fffu + ((v.u >> 16) & 1u);   // RNE
    return (unsigned short)(r >> 16);
}
__device__ __forceinline__ float bf2f(unsigned short h) {
    union { unsigned u; float f; } v; v.u = ((unsigned)h) << 16;
    return v.f;
}
// packed f32x2 -> bf16x2 (v_cvt_pk_bf16_f32), RNE
__device__ __forceinline__ unsigned pk2(float x, float y) {
    union { __hip_bfloat162 h; unsigned u; } c;
    c.h = __float22bfloat162_rn(float2{x, y});
    return c.u;
}

// ---- prep: blocks [0, u2e_blocks) GRID-STRIDE cast u2e fp32 -> bf16
//      (R10 post-mortem: 1-iter/thread version ran at 2.3 TB/s, 36% of BW
//       ceiling; grid-stride streaming is the G11/G13 pattern);
//      blocks [u2e_blocks, +192): W1 -> W1t bf16 [n][k], W2 -> W2t [n][k]
__global__ __launch_bounds__(256) void prep_kernel(
    const float* __restrict__ u2e, const float* __restrict__ W1, const float* __restrict__ W2,
    unsigned short* __restrict__ u2e_bf, unsigned short* __restrict__ W1t,
    unsigned short* __restrict__ W2t, const int u2e_blocks, const long Vd)
{
    const int b = blockIdx.x;
    if (b < u2e_blocks) {
        const long stride = (long)u2e_blocks * 256 * 8;
        for (long i = ((long)b * 256 + threadIdx.x) * 8; i < Vd; i += stride) {
            const float4 v0 = *(const float4*)(u2e + i);
            const float4 v1 = *(const float4*)(u2e + i + 4);
            uint4 p;
            p.x = pk2(v0.x, v0.y); p.y = pk2(v0.z, v0.w);
            p.z = pk2(v1.x, v1.y); p.w = pk2(v1.z, v1.w);
            *(uint4*)(u2e_bf + i) = p;
        }
    } else {
        const int id = (b - u2e_blocks) * 256 + threadIdx.x;   // 0..49151
        if (id < 256 * 128) {
            const int n = id >> 8, k = id & 255;
            W1t[id] = f2bf(W1[k * DD + n]);
        } else {
            const int j = id - 256 * 128;
            const int n = j >> 7, k = j & 127;
            W2t[j] = f2bf(W2[k * DD + n]);
        }
    }
}

template<bool BF>
__global__ __launch_bounds__(256, 2) void ppagg_mfma(
    const int* __restrict__ nodes, const int* __restrict__ neigh,
    const int* __restrict__ degrees, const float* __restrict__ u2e,
    const unsigned short* __restrict__ u2e_bf,
    const unsigned short* __restrict__ W1t, const unsigned short* __restrict__ W2t,
    const float* __restrict__ b1, const float* __restrict__ b2,
    const float* __restrict__ W3, const float* __restrict__ b3,
    float* __restrict__ out, const int Nn)
{
    // R10 structure (123 us, self-half hoisted) MINUS the B5 barrier:
    // softmax is computed IN-WAVE from s_part (each wave owns one node's 32
    // rows; identical reduce tree -> bit-identical results), attention
    // broadcast via __shfl. This lets the it1 prefetch gather stay in flight
    // across softmax + epilogue (B5's implicit vmcnt(0) used to force it to
    // complete early). RULE (R2/R3/R6): gathered rows never live in registers
    // across a phase -- load -> immediate ds_write only.
    __shared__ __align__(16) unsigned short s_A[128 * SE];   // 34.8 KB
    __shared__ __align__(16) unsigned short s_B[128 * SE];   // 34.8 KB
    __shared__ __align__(16) unsigned short s_x8[8 * DD];    // 8 self vecs bf16 (2 KB)
    __shared__ float s_selfc[8 * 128];                        // self.W1self + b1 (4 KB)
    __shared__ float s_part[4][128];                          // per-wave logit partials

    const int tid  = threadIdx.x;
    const int w    = tid >> 6;     // wave id = node owner in softmax/epilogue
    const int lane = tid & 63;
    const int ln   = lane & 15;
    const int q    = lane >> 4;    // quad

    const int nb = blockIdx.x * 8;
    const int r  = tid & 127;      // staged row
    const int h  = tid >> 7;       // col half (0: 0..63, 1: 64..127)

    // ---- prologue: both iters' indices + validity ----
    // deg gating: slots k >= deg get exactly-zero attention (NEG logit ->
    // exp underflow -> att == 0.0f) -> skip their gather, stage zeros.
    int idxA, idxB, vA, vB;
    {
        int ng0 = nb + (r >> 5);       if (ng0 >= Nn) ng0 = Nn - 1;
        int ng1 = nb + 4 + (r >> 5);   if (ng1 >= Nn) ng1 = Nn - 1;
        idxA = neigh[ng0 * KK + (r & 31)];
        idxB = neigh[ng1 * KK + (r & 31)];
        vA = (r & 31) < degrees[ng0];
        vB = (r & 31) < degrees[ng1];
    }

    // ---- stage: half-row per thread, load -> immediate ds_write ----
    auto stage = [&](unsigned short* buf, int idx, int v) {
        unsigned short* dst = buf + r * SE + h * 64;
        if (BF && v) {
            const uint4* src = (const uint4*)(u2e_bf + (long)idx * DD + h * 64);
            #pragma unroll
            for (int c = 0; c < 8; ++c) *(uint4*)(dst + c * 8) = src[c];
        } else if (!BF && v) {
            const float4* src = (const float4*)(u2e + (long)idx * DD + h * 64);
            #pragma unroll
            for (int c8 = 0; c8 < 8; ++c8) {
                const float4 v0 = src[c8 * 2];
                const float4 v1 = src[c8 * 2 + 1];
                uint4 p;
                p.x = pk2(v0.x, v0.y); p.y = pk2(v0.z, v0.w);
                p.z = pk2(v1.x, v1.y); p.w = pk2(v1.z, v1.w);
                *(uint4*)(dst + c8 * 8) = p;
            }
        } else {
            const uint4 z = {0u, 0u, 0u, 0u};
            #pragma unroll
            for (int c = 0; c < 8; ++c) *(uint4*)(dst + c * 8) = z;
        }
    };

    // ---- it0 stage into s_A (issues first: longest-latency loads) ----
    stage(s_A, idxA, vA);

    // ---- all 8 self vectors -> s_x8 (bf16; feeds the prologue self-GEMM) ----
    {
        int gn = nb + (tid >> 5); if (gn >= Nn) gn = Nn - 1;
        const int g = tid >> 5, p = tid & 31;
        const float4 v = *(const float4*)(u2e + (long)nodes[gn] * DD + p * 4);
        *(unsigned*)(s_x8 + g * DD + p * 4)     = pk2(v.x, v.y);
        *(unsigned*)(s_x8 + g * DD + p * 4 + 2) = pk2(v.z, v.w);
    }

    // epilogue self values (fp32, exact): wave w owns node w of each half
    float2 self0, self1;
    {
        int n0 = nb + w;       if (n0 >= Nn) n0 = Nn - 1;
        int n1 = nb + 4 + w;   if (n1 >= Nn) n1 = Nn - 1;
        self0 = *(const float2*)(u2e + (long)nodes[n0] * DD + lane * 2);
        self1 = *(const float2*)(u2e + (long)nodes[n1] * DD + lane * 2);
    }

    // ---- weight fragments in registers (e-half of W1 only + W2) ----
    // B-frag (16x16x32): B[k = q*8+j][n = ln]; W1t/W2t are [n][k] -> contiguous 16 B
    bf16x8 b1f[4][2], b2f[4][2];
    float b1c[2], b2c[2], w3c[2];
    const int c0 = w * 32 + ln;       // owned col, nt=0
    const int c1 = c0 + 16;           // owned col, nt=1
    #pragma unroll
    for (int kk = 0; kk < 4; ++kk) {
        b1f[kk][0] = *(const bf16x8*)(W1t + c0 * 256 + kk * 32 + q * 8);
        b1f[kk][1] = *(const bf16x8*)(W1t + c1 * 256 + kk * 32 + q * 8);
        b2f[kk][0] = *(const bf16x8*)(W2t + c0 * 128 + kk * 32 + q * 8);
        b2f[kk][1] = *(const bf16x8*)(W2t + c1 * 128 + kk * 32 + q * 8);
    }
    b1c[0] = b1[c0]; b1c[1] = b1[c1];
    b2c[0] = b2[c0]; b2c[1] = b2[c1];
    w3c[0] = W3[c0]; w3c[1] = W3[c1];
    const float b3v = b3[0];

    __syncthreads();   // P1: s_x8 ready (it0 stage writes also drained)

    // ---- prologue self-GEMM: s_selfc[g][c] = self[g].W1self[:,c] + b1[c] ----
    {
        f32x4 a0 = (f32x4){0.f,0.f,0.f,0.f}, a1 = (f32x4){0.f,0.f,0.f,0.f};
        #pragma unroll
        for (int kk = 0; kk < 4; ++kk) {
            const bf16x8 av = *(const bf16x8*)(s_x8 + (ln & 7) * DD + kk * 32 + q * 8);
            const bf16x8 w0 = *(const bf16x8*)(W1t + c0 * 256 + 128 + kk * 32 + q * 8);
            const bf16x8 w1 = *(const bf16x8*)(W1t + c1 * 256 + 128 + kk * 32 + q * 8);
            a0 = __builtin_amdgcn_mfma_f32_16x16x32_bf16(av, w0, a0, 0, 0, 0);
            a1 = __builtin_amdgcn_mfma_f32_16x16x32_bf16(av, w1, a1, 0, 0, 0);
        }
        if (q < 2) {
            #pragma unroll
            for (int rr = 0; rr < 4; ++rr) {
                s_selfc[(q * 4 + rr) * 128 + c0] = a0[rr] + b1c[0];
                s_selfc[(q * 4 + rr) * 128 + c1] = a1[rr] + b1c[1];
            }
        }
    }
    __syncthreads();   // B1 (it0): s_selfc ready; e-tile ready since P1

    #pragma unroll
    for (int it = 0; it < 2; ++it) {
        unsigned short* E = it ? s_B : s_A;   // e-tile of this iter
        unsigned short* H = it ? s_A : s_B;   // h1 scratch of this iter
        const int gbase = nb + it * 4;        // rows 0..127 = (g=row>>5, k=row&31)
        const float2 selfv = it ? self1 : self0;

        if (it == 1) __syncthreads();   // B1 (it1): s_B staged (from it0's tail)

        // ---------- layer 1 (e-half only): C[128x128] = e[128x128] x W1e ----------
        f32x4 acc[8][2];
        #pragma unroll
        for (int mt = 0; mt < 8; ++mt) {
            acc[mt][0] = (f32x4){0.f, 0.f, 0.f, 0.f};
            acc[mt][1] = (f32x4){0.f, 0.f, 0.f, 0.f};
        }
        #pragma unroll
        for (int kk = 0; kk < 4; ++kk) {
            bf16x8 a[8];
            #pragma unroll
            for (int mt = 0; mt < 8; ++mt)
                a[mt] = *(const bf16x8*)(E + (mt * 16 + ln) * SE + kk * 32 + q * 8);
            #pragma unroll
            for (int mt = 0; mt < 8; ++mt) {
                acc[mt][0] = __builtin_amdgcn_mfma_f32_16x16x32_bf16(a[mt], b1f[kk][0], acc[mt][0], 0, 0, 0);
                acc[mt][1] = __builtin_amdgcn_mfma_f32_16x16x32_bf16(a[mt], b1f[kk][1], acc[mt][1], 0, 0, 0);
            }
        }
        // h1 = relu(acc + selfc(node,col)) -> bf16 -> H  (selfc includes b1;
        // node of rows [mt*16, mt*16+15] = mt>>1).
        #pragma unroll
        for (int mt = 0; mt < 8; ++mt) {
            const float sc0 = s_selfc[(it * 4 + (mt >> 1)) * 128 + c0];
            const float sc1 = s_selfc[(it * 4 + (mt >> 1)) * 128 + c1];
            #pragma unroll
            for (int rr = 0; rr < 4; rr += 2) {
                const int row = mt * 16 + q * 4 + rr;
                const unsigned p0 = pk2(fmaxf(acc[mt][0][rr]     + sc0, 0.f),
                                        fmaxf(acc[mt][0][rr + 1] + sc0, 0.f));
                const unsigned p1v = pk2(fmaxf(acc[mt][1][rr]     + sc1, 0.f),
                                         fmaxf(acc[mt][1][rr + 1] + sc1, 0.f));
                H[row * SE + c0]       = (unsigned short)(p0 & 0xffffu);
                H[(row + 1) * SE + c0] = (unsigned short)(p0 >> 16);
                H[row * SE + c1]       = (unsigned short)(p1v & 0xffffu);
                H[(row + 1) * SE + c1] = (unsigned short)(p1v >> 16);
            }
        }
        __syncthreads();   // B3: h1 ready

        // ---------- layer 2 + fused logit: h2 never touches LDS ----------
        f32x4 acc2[8][2];
        #pragma unroll
        for (int mt = 0; mt < 8; ++mt) {
            acc2[mt][0] = (f32x4){0.f, 0.f, 0.f, 0.f};
            acc2[mt][1] = (f32x4){0.f, 0.f, 0.f, 0.f};
        }
        #pragma unroll
        for (int kk = 0; kk < 4; ++kk) {
            bf16x8 a[8];
            #pragma unroll
            for (int mt = 0; mt < 8; ++mt)
                a[mt] = *(const bf16x8*)(H + (mt * 16 + ln) * SE + kk * 32 + q * 8);
            #pragma unroll
            for (int mt = 0; mt < 8; ++mt) {
                acc2[mt][0] = __builtin_amdgcn_mfma_f32_16x16x32_bf16(a[mt], b2f[kk][0], acc2[mt][0], 0, 0, 0);
                acc2[mt][1] = __builtin_amdgcn_mfma_f32_16x16x32_bf16(a[mt], b2f[kk][1], acc2[mt][1], 0, 0, 0);
            }
        }
        // per-thread logit partials reduced over the 16-lane col group
        #pragma unroll
        for (int mt = 0; mt < 8; ++mt) {
            float p[4];
            #pragma unroll
            for (int rr = 0; rr < 4; ++rr) {
                const float h0 = fmaxf(acc2[mt][0][rr] + b2c[0], 0.f);
                const float h1v = fmaxf(acc2[mt][1][rr] + b2c[1], 0.f);
                p[rr] = fmaf(h0, w3c[0], h1v * w3c[1]);
            }
            #pragma unroll
            for (int off = 1; off < 16; off <<= 1) {
                #pragma unroll
                for (int rr = 0; rr < 4; ++rr) p[rr] += __shfl_xor(p[rr], off);
            }
            if (ln == 0) {
                const int row0 = mt * 16 + q * 4;
                #pragma unroll
                for (int rr = 0; rr < 4; ++rr) s_part[w][row0 + rr] = p[rr];
            }
        }
        __syncthreads();   // B4: partials ready; H's (h1) readers all done

        // ---- it1 stage into s_B (free past B4): load -> immediate ds_write.
        //      With B5 gone, these gathers stay in flight through softmax AND
        //      the epilogue; they only drain at B1(it1). ----
        if (it == 0) stage(s_B, idxB, vB);

        // ---------- in-wave masked softmax + epilogue (no barrier) ----------
        // wave w owns node gbase+w; lane handles row (lane&31); both 32-halves
        // compute identical values (same reduce tree as before -> bit-identical).
        {
            const int ng  = gbase + w;
            const int ngc = (ng < Nn) ? ng : Nn - 1;
            const int deg = degrees[ngc];
            const int krow = lane & 31;
            const int rb = w * KK;
            const float logit = s_part[0][rb + krow] + s_part[1][rb + krow]
                              + s_part[2][rb + krow] + s_part[3][rb + krow] + b3v;
            const float ml = (krow < deg) ? logit : NEGV;
            float mx = ml;
            #pragma unroll
            for (int off = 16; off > 0; off >>= 1) mx = fmaxf(mx, __shfl_xor(mx, off));
            const float e = __expf(ml - mx);
            float ssum = e;
            #pragma unroll
            for (int off = 16; off > 0; off >>= 1) ssum += __shfl_xor(ssum, off);
            const float att = e / ssum;

            // aggregation straight from the LDS e-tile
            const int degw = (ng < Nn) ? deg : 0;
            float ax = 0.f, ay = 0.f;
            for (int k = 0; k < degw; ++k) {
                const float a = __shfl(att, k, 32);
                const unsigned pe = *(const unsigned*)(E + (rb + k) * SE + lane * 2);
                ax = fmaf(a, bf2f((unsigned short)(pe & 0xffffu)), ax);
                ay = fmaf(a, bf2f((unsigned short)(pe >> 16)), ay);
            }
            if (ng < Nn) {
                float2 o;
                o.x = (degw > 0) ? 0.5f * (ax + selfv.x) : selfv.x;
                o.y = (degw > 0) ? 0.5f * (ay + selfv.y) : selfv.y;
                *(float2*)(out + (long)ng * DD + lane * 2) = o;
            }
        }
        // no trailing barrier: next iter's first touch of shared state is the
        // B1(it1) barrier at loop top (E of it1 = s_B already staged above).
    }
}

extern "C" void kernel_launch(void* const* d_in, const int* in_sizes, int n_in,
                              void* d_out, int out_size, void* d_ws, size_t ws_size,
                              hipStream_t stream) {
    const int*   nodes   = (const int*)d_in[0];
    const int*   neigh   = (const int*)d_in[1];
    const int*   degrees = (const int*)d_in[2];
    const float* u2e     = (const float*)d_in[3];
    const float* W1      = (const float*)d_in[4];
    const float* b1      = (const float*)d_in[5];
    const float* W2      = (const float*)d_in[6];
    const float* b2      = (const float*)d_in[7];
    const float* W3      = (const float*)d_in[8];
    const float* b3      = (const float*)d_in[9];
    float* out = (float*)d_out;

    const int  Nn = in_sizes[0];          // 20000
    const long Vd = (long)in_sizes[3];    // V*D = 12,800,000

    unsigned short* W1t = (unsigned short*)d_ws;        // 64 KB
    unsigned short* W2t = W1t + 256 * 128;              // 32 KB
    unsigned short* u2e_bf = W2t + 128 * 128;           // V*D bf16 = 25.6 MB

    const size_t need_bf = (size_t)(256 * 128 + 128 * 128) * 2 + (size_t)Vd * 2;
    const bool use_bf = (ws_size >= need_bf) && (Vd % 8 == 0);
    const int u2e_blocks = use_bf ? PREP_BLKS : 0;

    prep_kernel<<<u2e_blocks + 192, 256, 0, stream>>>(u2e, W1, W2, u2e_bf, W1t, W2t,
                                                      u2e_blocks, Vd);

    const int grid = (Nn + 7) / 8;
    if (use_bf)
        ppagg_mfma<true><<<grid, 256, 0, stream>>>(nodes, neigh, degrees, u2e, u2e_bf,
                                                   W1t, W2t, b1, b2, W3, b3, out, Nn);
    else
        ppagg_mfma<false><<<grid, 256, 0, stream>>>(nodes, neigh, degrees, u2e, nullptr,
                                                    W1t, W2t, b1, b2, W3, b3, out, Nn);
}

// Round 12
// 204.190 us; speedup vs baseline: 1.1092x; 1.1092x over previous
//
#include <hip/hip_runtime.h>
#include <hip/hip_bf16.h>

#define KK 32
#define DD 128
#define NEGV (-1e9f)
#define SE 136   // LDS row stride in ushorts: 272 B, 16-B aligned, non-pow2 banks
#define PREP_BLKS 2048

typedef __attribute__((ext_vector_type(8))) short bf16x8;
typedef __attribute__((ext_vector_type(4))) float f32x4;

__device__ __forceinline__ unsigned short f2bf(float f) {
    union { float f; unsigned u; } v; v.f = f;
    unsigned r = v.u + 0x7fffu + ((v.u >> 16) & 1u);   // RNE
    return (unsigned short)(r >> 16);
}
__device__ __forceinline__ float bf2f(unsigned short h) {
    union { unsigned u; float f; } v; v.u = ((unsigned)h) << 16;
    return v.f;
}
// packed f32x2 -> bf16x2 (v_cvt_pk_bf16_f32), RNE
__device__ __forceinline__ unsigned pk2(float x, float y) {
    union { __hip_bfloat162 h; unsigned u; } c;
    c.h = __float22bfloat162_rn(float2{x, y});
    return c.u;
}

// ---- prep: blocks [0, u2e_blocks) grid-stride cast u2e fp32 -> bf16;
//      blocks [u2e_blocks, +192): W1 -> W1t bf16 [n][k], W2 -> W2t [n][k]
__global__ __launch_bounds__(256) void prep_kernel(
    const float* __restrict__ u2e, const float* __restrict__ W1, const float* __restrict__ W2,
    unsigned short* __restrict__ u2e_bf, unsigned short* __restrict__ W1t,
    unsigned short* __restrict__ W2t, const int u2e_blocks, const long Vd)
{
    const int b = blockIdx.x;
    if (b < u2e_blocks) {
        const long stride = (long)u2e_blocks * 256 * 8;
        for (long i = ((long)b * 256 + threadIdx.x) * 8; i < Vd; i += stride) {
            const float4 v0 = *(const float4*)(u2e + i);
            const float4 v1 = *(const float4*)(u2e + i + 4);
            uint4 p;
            p.x = pk2(v0.x, v0.y); p.y = pk2(v0.z, v0.w);
            p.z = pk2(v1.x, v1.y); p.w = pk2(v1.z, v1.w);
            *(uint4*)(u2e_bf + i) = p;
        }
    } else {
        const int id = (b - u2e_blocks) * 256 + threadIdx.x;   // 0..49151
        if (id < 256 * 128) {
            const int n = id >> 8, k = id & 255;
            W1t[id] = f2bf(W1[k * DD + n]);
        } else {
            const int j = id - 256 * 128;
            const int n = j >> 7, k = j & 127;
            W2t[j] = f2bf(W2[k * DD + n]);
        }
    }
}

template<bool BF>
__global__ __launch_bounds__(256, 2) void ppagg_mfma(
    const int* __restrict__ nodes, const int* __restrict__ neigh,
    const int* __restrict__ degrees, const float* __restrict__ u2e,
    const unsigned short* __restrict__ u2e_bf,
    const unsigned short* __restrict__ W1t, const unsigned short* __restrict__ W2t,
    const float* __restrict__ b1, const float* __restrict__ b2,
    const float* __restrict__ W3, const float* __restrict__ b3,
    float* __restrict__ out, const int Nn)
{
    // R10 structure (123 us: dual-tile role-swap, LDS epilogue, self-hoist,
    // B5+s_att softmax) + OPERAND-SWAPPED MFMAs: mfma(W_frag, e_frag) yields
    // the transposed C (A/B frags have identical per-lane layouts, so the LDS
    // reads are unchanged). Each lane then holds 4 CONSECUTIVE output features
    // at a fixed e-row:
    //   * h1 writes: 16 ds_write_b64 instead of 64 ds_write_b16
    //   * logit reduce: 16 shfl_xor instead of 128 (sum over own 8 features,
    //     then reduce over the 4 quads)
    // RULE (R2/R3/R6): gathered rows never live in registers across a phase.
    __shared__ __align__(16) unsigned short s_A[128 * SE];   // 34.8 KB
    __shared__ __align__(16) unsigned short s_B[128 * SE];   // 34.8 KB
    __shared__ __align__(16) unsigned short s_x8[8 * DD];    // 8 self vecs bf16 (2 KB)
    __shared__ __align__(16) float s_selfc[8 * 128];          // self.W1self + b1 (4 KB)
    __shared__ __align__(16) float s_b2w3[256];               // b2 | W3 (1 KB)
    __shared__ float s_part[4][128];                          // per-wave logit partials
    __shared__ float s_att[128];

    const int tid  = threadIdx.x;
    const int w    = tid >> 6;     // wave id = node owner in epilogue
    const int lane = tid & 63;
    const int ln   = lane & 15;
    const int q    = lane >> 4;    // quad

    const int nb = blockIdx.x * 8;
    const int r  = tid & 127;      // staged row
    const int h  = tid >> 7;       // col half (0: 0..63, 1: 64..127)

    // ---- prologue: both iters' indices + validity ----
    // deg gating: slots k >= deg get exactly-zero attention (NEG logit ->
    // exp underflow -> att == 0.0f) -> skip their gather, stage zeros.
    int idxA, idxB, vA, vB;
    {
        int ng0 = nb + (r >> 5);       if (ng0 >= Nn) ng0 = Nn - 1;
        int ng1 = nb + 4 + (r >> 5);   if (ng1 >= Nn) ng1 = Nn - 1;
        idxA = neigh[ng0 * KK + (r & 31)];
        idxB = neigh[ng1 * KK + (r & 31)];
        vA = (r & 31) < degrees[ng0];
        vB = (r & 31) < degrees[ng1];
    }

    // ---- stage: half-row per thread, load -> immediate ds_write ----
    auto stage = [&](unsigned short* buf, int idx, int v) {
        unsigned short* dst = buf + r * SE + h * 64;
        if (BF && v) {
            const uint4* src = (const uint4*)(u2e_bf + (long)idx * DD + h * 64);
            #pragma unroll
            for (int c = 0; c < 8; ++c) *(uint4*)(dst + c * 8) = src[c];
        } else if (!BF && v) {
            const float4* src = (const float4*)(u2e + (long)idx * DD + h * 64);
            #pragma unroll
            for (int c8 = 0; c8 < 8; ++c8) {
                const float4 v0 = src[c8 * 2];
                const float4 v1 = src[c8 * 2 + 1];
                uint4 p;
                p.x = pk2(v0.x, v0.y); p.y = pk2(v0.z, v0.w);
                p.z = pk2(v1.x, v1.y); p.w = pk2(v1.z, v1.w);
                *(uint4*)(dst + c8 * 8) = p;
            }
        } else {
            const uint4 z = {0u, 0u, 0u, 0u};
            #pragma unroll
            for (int c = 0; c < 8; ++c) *(uint4*)(dst + c * 8) = z;
        }
    };

    // ---- it0 stage into s_A (issues first: longest-latency loads) ----
    stage(s_A, idxA, vA);

    // ---- all 8 self vectors -> s_x8; b2/W3 -> s_b2w3 ----
    {
        int gn = nb + (tid >> 5); if (gn >= Nn) gn = Nn - 1;
        const int g = tid >> 5, p = tid & 31;
        const float4 v = *(const float4*)(u2e + (long)nodes[gn] * DD + p * 4);
        *(unsigned*)(s_x8 + g * DD + p * 4)     = pk2(v.x, v.y);
        *(unsigned*)(s_x8 + g * DD + p * 4 + 2) = pk2(v.z, v.w);
        s_b2w3[tid] = (tid < 128) ? b2[tid] : W3[tid - 128];
    }

    // epilogue self values (fp32, exact): wave w owns node w of each half
    float2 self0, self1;
    {
        int n0 = nb + w;       if (n0 >= Nn) n0 = Nn - 1;
        int n1 = nb + 4 + w;   if (n1 >= Nn) n1 = Nn - 1;
        self0 = *(const float2*)(u2e + (long)nodes[n0] * DD + lane * 2);
        self1 = *(const float2*)(u2e + (long)nodes[n1] * DD + lane * 2);
    }

    // ---- weight fragments in registers (e-half of W1 only + W2) ----
    // frag layout (both roles): lane&15 <-> non-K dim, k = q*8+j; 16 B contiguous
    bf16x8 b1f[4][2], b2f[4][2];
    float b1c[2];
    const int c0 = w * 32 + ln;       // owned col, nt=0
    const int c1 = c0 + 16;           // owned col, nt=1
    #pragma unroll
    for (int kk = 0; kk < 4; ++kk) {
        b1f[kk][0] = *(const bf16x8*)(W1t + c0 * 256 + kk * 32 + q * 8);
        b1f[kk][1] = *(const bf16x8*)(W1t + c1 * 256 + kk * 32 + q * 8);
        b2f[kk][0] = *(const bf16x8*)(W2t + c0 * 128 + kk * 32 + q * 8);
        b2f[kk][1] = *(const bf16x8*)(W2t + c1 * 128 + kk * 32 + q * 8);
    }
    b1c[0] = b1[c0]; b1c[1] = b1[c1];
    const float b3v = b3[0];

    __syncthreads();   // P1: s_x8 + s_b2w3 ready (it0 stage writes also drained)

    // ---- prologue self-GEMM: s_selfc[g][c] = self[g].W1self[:,c] + b1[c] ----
    {
        f32x4 a0 = (f32x4){0.f,0.f,0.f,0.f}, a1 = (f32x4){0.f,0.f,0.f,0.f};
        #pragma unroll
        for (int kk = 0; kk < 4; ++kk) {
            const bf16x8 av = *(const bf16x8*)(s_x8 + (ln & 7) * DD + kk * 32 + q * 8);
            const bf16x8 w0 = *(const bf16x8*)(W1t + c0 * 256 + 128 + kk * 32 + q * 8);
            const bf16x8 w1 = *(const bf16x8*)(W1t + c1 * 256 + 128 + kk * 32 + q * 8);
            a0 = __builtin_amdgcn_mfma_f32_16x16x32_bf16(av, w0, a0, 0, 0, 0);
            a1 = __builtin_amdgcn_mfma_f32_16x16x32_bf16(av, w1, a1, 0, 0, 0);
        }
        if (q < 2) {
            #pragma unroll
            for (int rr = 0; rr < 4; ++rr) {
                s_selfc[(q * 4 + rr) * 128 + c0] = a0[rr] + b1c[0];
                s_selfc[(q * 4 + rr) * 128 + c1] = a1[rr] + b1c[1];
            }
        }
    }
    __syncthreads();   // B1 (it0): s_selfc ready; e-tile ready since P1

    #pragma unroll
    for (int it = 0; it < 2; ++it) {
        unsigned short* E = it ? s_B : s_A;   // e-tile of this iter
        unsigned short* H = it ? s_A : s_B;   // h1 scratch of this iter
        const int gbase = nb + it * 4;        // rows 0..127 = (g=row>>5, k=row&31)
        const float2 selfv = it ? self1 : self0;

        if (it == 1) __syncthreads();   // B1 (it1): s_B staged (from it0's tail)

        // ---------- layer 1 (e-half only), SWAPPED: acc' = h1^T fragments ----------
        // acc[mt][nt][rr] = h1[row = mt*16+ln][n = w*32 + nt*16 + q*4 + rr]
        f32x4 acc[8][2];
        #pragma unroll
        for (int mt = 0; mt < 8; ++mt) {
            acc[mt][0] = (f32x4){0.f, 0.f, 0.f, 0.f};
            acc[mt][1] = (f32x4){0.f, 0.f, 0.f, 0.f};
        }
        #pragma unroll
        for (int kk = 0; kk < 4; ++kk) {
            bf16x8 a[8];
            #pragma unroll
            for (int mt = 0; mt < 8; ++mt)
                a[mt] = *(const bf16x8*)(E + (mt * 16 + ln) * SE + kk * 32 + q * 8);
            #pragma unroll
            for (int mt = 0; mt < 8; ++mt) {
                acc[mt][0] = __builtin_amdgcn_mfma_f32_16x16x32_bf16(b1f[kk][0], a[mt], acc[mt][0], 0, 0, 0);
                acc[mt][1] = __builtin_amdgcn_mfma_f32_16x16x32_bf16(b1f[kk][1], a[mt], acc[mt][1], 0, 0, 0);
            }
        }
        // h1 = relu(acc + selfc(node, n)) -> bf16 -> H: one b64 write per (mt,nt)
        #pragma unroll
        for (int mt = 0; mt < 8; ++mt) {
            const int node = it * 4 + (mt >> 1);
            #pragma unroll
            for (int nt = 0; nt < 2; ++nt) {
                const int nb4 = w * 32 + nt * 16 + q * 4;
                const f32x4 sc = *(const f32x4*)(s_selfc + node * 128 + nb4);
                uint2 pw;
                pw.x = pk2(fmaxf(acc[mt][nt][0] + sc[0], 0.f),
                           fmaxf(acc[mt][nt][1] + sc[1], 0.f));
                pw.y = pk2(fmaxf(acc[mt][nt][2] + sc[2], 0.f),
                           fmaxf(acc[mt][nt][3] + sc[3], 0.f));
                *(uint2*)(H + (mt * 16 + ln) * SE + nb4) = pw;
            }
        }
        __syncthreads();   // B3: h1 ready

        // ---------- layer 2 + fused logit, SWAPPED ----------
        // acc2[mt][nt][rr] = h2[row = mt*16+ln][n = w*32 + nt*16 + q*4 + rr]
        f32x4 acc2[8][2];
        #pragma unroll
        for (int mt = 0; mt < 8; ++mt) {
            acc2[mt][0] = (f32x4){0.f, 0.f, 0.f, 0.f};
            acc2[mt][1] = (f32x4){0.f, 0.f, 0.f, 0.f};
        }
        #pragma unroll
        for (int kk = 0; kk < 4; ++kk) {
            bf16x8 a[8];
            #pragma unroll
            for (int mt = 0; mt < 8; ++mt)
                a[mt] = *(const bf16x8*)(H + (mt * 16 + ln) * SE + kk * 32 + q * 8);
            #pragma unroll
            for (int mt = 0; mt < 8; ++mt) {
                acc2[mt][0] = __builtin_amdgcn_mfma_f32_16x16x32_bf16(b2f[kk][0], a[mt], acc2[mt][0], 0, 0, 0);
                acc2[mt][1] = __builtin_amdgcn_mfma_f32_16x16x32_bf16(b2f[kk][1], a[mt], acc2[mt][1], 0, 0, 0);
            }
        }
        // logit partial: each lane sums relu(h2+b2)*w3 over its OWN 8 features,
        // then reduces over the 4 quads (2 shfl) -> lane<16 writes row partial.
        {
            const f32x4 b2v0 = *(const f32x4*)(s_b2w3 + w * 32 + q * 4);
            const f32x4 b2v1 = *(const f32x4*)(s_b2w3 + w * 32 + 16 + q * 4);
            const f32x4 w3v0 = *(const f32x4*)(s_b2w3 + 128 + w * 32 + q * 4);
            const f32x4 w3v1 = *(const f32x4*)(s_b2w3 + 128 + w * 32 + 16 + q * 4);
            #pragma unroll
            for (int mt = 0; mt < 8; ++mt) {
                float pl = 0.f;
                #pragma unroll
                for (int rr = 0; rr < 4; ++rr) {
                    pl = fmaf(fmaxf(acc2[mt][0][rr] + b2v0[rr], 0.f), w3v0[rr], pl);
                    pl = fmaf(fmaxf(acc2[mt][1][rr] + b2v1[rr], 0.f), w3v1[rr], pl);
                }
                pl += __shfl_xor(pl, 16);
                pl += __shfl_xor(pl, 32);
                if (lane < 16) s_part[w][mt * 16 + ln] = pl;
            }
        }
        __syncthreads();   // B4: partials ready; H's (h1) readers all done

        // ---- it1 stage into s_B (free past B4): load -> immediate ds_write;
        //      latency overlaps softmax + epilogue below. ----
        if (it == 0) stage(s_B, idxB, vB);

        // ---------- masked softmax (threads 0..127; shfl within 32-groups) ----------
        if (tid < 128) {
            const int row = tid;
            const float logit = s_part[0][row] + s_part[1][row] + s_part[2][row] + s_part[3][row] + b3v;
            int ng = gbase + (row >> 5);
            if (ng >= Nn) ng = Nn - 1;
            const int deg = degrees[ng];
            const float ml = ((row & 31) < deg) ? logit : NEGV;
            float mx = ml;
            #pragma unroll
            for (int off = 16; off > 0; off >>= 1) mx = fmaxf(mx, __shfl_xor(mx, off));
            const float e = __expf(ml - mx);
            float ssum = e;
            #pragma unroll
            for (int off = 16; off > 0; off >>= 1) ssum += __shfl_xor(ssum, off);
            s_att[row] = e / ssum;
        }
        __syncthreads();   // B5: s_att ready

        // ---------- epilogue: aggregation straight from the LDS e-tile ----------
        {
            const int ng = gbase + w;
            const int degw = (ng < Nn) ? degrees[ng] : 0;
            float ax = 0.f, ay = 0.f;
            for (int k = 0; k < degw; ++k) {
                const float a = s_att[w * KK + k];
                const unsigned pe = *(const unsigned*)(E + (w * KK + k) * SE + lane * 2);
                ax = fmaf(a, bf2f((unsigned short)(pe & 0xffffu)), ax);
                ay = fmaf(a, bf2f((unsigned short)(pe >> 16)), ay);
            }
            if (ng < Nn) {
                float2 o;
                o.x = (degw > 0) ? 0.5f * (ax + selfv.x) : selfv.x;
                o.y = (degw > 0) ? 0.5f * (ay + selfv.y) : selfv.y;
                *(float2*)(out + (long)ng * DD + lane * 2) = o;
            }
        }
        // no trailing barrier: next iter's first touch of shared state is the
        // B1(it1) barrier at loop top (E of it1 = s_B already staged above).
    }
}

extern "C" void kernel_launch(void* const* d_in, const int* in_sizes, int n_in,
                              void* d_out, int out_size, void* d_ws, size_t ws_size,
                              hipStream_t stream) {
    const int*   nodes   = (const int*)d_in[0];
    const int*   neigh   = (const int*)d_in[1];
    const int*   degrees = (const int*)d_in[2];
    const float* u2e     = (const float*)d_in[3];
    const float* W1      = (const float*)d_in[4];
    const float* b1      = (const float*)d_in[5];
    const float* W2      = (const float*)d_in[6];
    const float* b2      = (const float*)d_in[7];
    const float* W3      = (const float*)d_in[8];
    const float* b3      = (const float*)d_in[9];
    float* out = (float*)d_out;

    const int  Nn = in_sizes[0];          // 20000
    const long Vd = (long)in_sizes[3];    // V*D = 12,800,000

    unsigned short* W1t = (unsigned short*)d_ws;        // 64 KB
    unsigned short* W2t = W1t + 256 * 128;              // 32 KB
    unsigned short* u2e_bf = W2t + 128 * 128;           // V*D bf16 = 25.6 MB

    const size_t need_bf = (size_t)(256 * 128 + 128 * 128) * 2 + (size_t)Vd * 2;
    const bool use_bf = (ws_size >= need_bf) && (Vd % 8 == 0);
    const int u2e_blocks = use_bf ? PREP_BLKS : 0;

    prep_kernel<<<u2e_blocks + 192, 256, 0, stream>>>(u2e, W1, W2, u2e_bf, W1t, W2t,
                                                      u2e_blocks, Vd);

    const int grid = (Nn + 7) / 8;
    if (use_bf)
        ppagg_mfma<true><<<grid, 256, 0, stream>>>(nodes, neigh, degrees, u2e, u2e_bf,
                                                   W1t, W2t, b1, b2, W3, b3, out, Nn);
    else
        ppagg_mfma<false><<<grid, 256, 0, stream>>>(nodes, neigh, degrees, u2e, nullptr,
                                                    W1t, W2t, b1, b2, W3, b3, out, Nn);
}